// Round 14
// baseline (276.557 us; speedup 1.0000x reference)
//
#include <hip/hip_runtime.h>
#include <cstdint>
#include <cstddef>

typedef __bf16 bf16;
typedef __bf16 bf16x8 __attribute__((ext_vector_type(8)));
typedef _Float16 f16;
typedef _Float16 f16x4 __attribute__((ext_vector_type(4)));
typedef _Float16 f16x8 __attribute__((ext_vector_type(8)));
typedef __fp16 fp16x2 __attribute__((ext_vector_type(2)));
typedef float f32x4 __attribute__((ext_vector_type(4)));

#define DEV static __device__ __forceinline__
#if __has_builtin(__builtin_amdgcn_exp2f)
#define EXP2(x) __builtin_amdgcn_exp2f(x)
#else
#define EXP2(x) exp2f(x)
#endif
#define QSCALE 0.18033688011112042f

DEV float gelu_exact(float v) {
  return 0.5f * v * (1.0f + erff(v * 0.70710678118654752f));
}

__global__ void cvt_w_kernel(const float* __restrict__ qkv_w, bf16* __restrict__ qwt,
                             const float* __restrict__ proj_w, bf16* __restrict__ pwt,
                             const float* __restrict__ f1w, bf16* __restrict__ f1wt,
                             const float* __restrict__ f2w, bf16* __restrict__ f2wt) {
  int blk = blockIdx.x;
  const float* w; bf16* o; int K, N;
  if (blk < 768)       { w = qkv_w;  o = qwt;  K = 256; N = 768; }
  else if (blk < 1024) { w = proj_w; o = pwt;  K = 256; N = 256; blk -= 768; }
  else if (blk < 1792) { w = f1w;    o = f1wt; K = 256; N = 768; blk -= 1024; }
  else                 { w = f2w;    o = f2wt; K = 768; N = 256; blk -= 1792; }
  const int idx = blk * 256 + threadIdx.x;
  const int n = idx / K, kk = idx - n * K;
  o[idx] = (bf16)w[(size_t)kk * N + n];
}

// ---------------- QKV GEMM (fp32 A staged->bf16), R10 structure -------------
__global__ __launch_bounds__(256, 2)
void gemm_qkv_kernel(const float* __restrict__ A, const bf16* __restrict__ Wt,
                     const float* __restrict__ bias, bf16* __restrict__ qb,
                     bf16* __restrict__ kb, f16* __restrict__ vt) {
  const int tid = threadIdx.x;
  const int wave = tid >> 6, lane = tid & 63;
  const int quad = lane >> 4, l15 = lane & 15;
  const int m0 = blockIdx.y * 128, n0 = blockIdx.x * 128;
  const int mw = (wave >> 1) * 64, nw = (wave & 1) * 64;
  const int K = 256;

  __shared__ bf16 lA[128 * 72];
  __shared__ bf16 lB[128 * 72];

  f32x4 acc[4][4] = {};

  for (int k0 = 0; k0 < K; k0 += 64) {
#pragma unroll
    for (int j = 0; j < 4; ++j) {
      const int c = j * 256 + tid;
      const int row = c >> 3, kc = (c & 7) * 8;
      const float* ax = A + (size_t)(m0 + row) * K + k0 + kc;
      const float4 a0 = *(const float4*)(ax);
      const float4 a1 = *(const float4*)(ax + 4);
      bf16x8 ab;
      ab[0] = (bf16)a0.x; ab[1] = (bf16)a0.y; ab[2] = (bf16)a0.z; ab[3] = (bf16)a0.w;
      ab[4] = (bf16)a1.x; ab[5] = (bf16)a1.y; ab[6] = (bf16)a1.z; ab[7] = (bf16)a1.w;
      *(bf16x8*)(lA + row * 72 + kc) = ab;
      *(uint4*)(lB + row * 72 + kc) =
          *(const uint4*)(Wt + (size_t)(n0 + row) * K + k0 + kc);
    }
    __syncthreads();
#pragma unroll
    for (int ks = 0; ks < 2; ++ks) {
      bf16x8 af[4], bfm[4];
#pragma unroll
      for (int i = 0; i < 4; ++i)
        af[i] = *(const bf16x8*)(lA + (mw + i * 16 + l15) * 72 + ks * 32 + quad * 8);
#pragma unroll
      for (int j = 0; j < 4; ++j)
        bfm[j] = *(const bf16x8*)(lB + (nw + j * 16 + l15) * 72 + ks * 32 + quad * 8);
#pragma unroll
      for (int i = 0; i < 4; ++i)
#pragma unroll
        for (int j = 0; j < 4; ++j)
          acc[i][j] = __builtin_amdgcn_mfma_f32_16x16x32_bf16(af[i], bfm[j],
                                                              acc[i][j], 0, 0, 0);
    }
    __syncthreads();
  }

  const bool isV = (n0 >= 512);
#pragma unroll
  for (int i = 0; i < 4; ++i) {
#pragma unroll
    for (int j = 0; j < 4; ++j) {
      const int n = n0 + nw + j * 16 + l15;
      const float bs = bias[n];
      if (isV) {
        const int m = m0 + mw + i * 16 + quad * 4;
        const int b = m >> 12, t = m & 4095;
        const int h = (n >> 6) & 3, d = n & 63;
        const int tp = (t & ~31) | (((t >> 2) & 3) << 3) | (((t >> 4) & 1) << 2);
        f16x4 hv;
#pragma unroll
        for (int r = 0; r < 4; ++r) hv[r] = (f16)(acc[i][j][r] + bs);
        *(f16x4*)(vt + (size_t)((b * 4 + h) * 64 + d) * 4096 + tp) = hv;
      } else {
        const int s = n >> 8, cc = n & 255, h = cc >> 6, d = cc & 63;
#pragma unroll
        for (int r = 0; r < 4; ++r) {
          const int m = m0 + mw + i * 16 + quad * 4 + r;
          const int b = m >> 12, t = m & 4095;
          const float v = acc[i][j][r] + bs;
          const size_t idx = (size_t)((b * 4 + h) * 4096 + t) * 64 + d;
          if (s == 0) qb[idx] = (bf16)(v * QSCALE);
          else        kb[idx] = (bf16)v;
        }
      }
    }
  }
}

// ---------------- flash attention: reg-prefetch dbuf, K=32 PV (R8-R10) ------
__global__ __launch_bounds__(256, 2)
void attn_kernel(const bf16* __restrict__ q, const bf16* __restrict__ k,
                 const f16* __restrict__ vt, bf16* __restrict__ o) {
  const int tid = threadIdx.x;
  const int wave = tid >> 6, lane = tid & 63;
  const int quad = lane >> 4, l15 = lane & 15;
  const int bh = blockIdx.y;
  const int q0 = blockIdx.x * 128;
  __shared__ bf16 lK[2][64 * 72];
  __shared__ f16  lV[2][64 * 72];

  bf16x8 qa0[2], qa1[2];
#pragma unroll
  for (int s = 0; s < 2; ++s) {
    const bf16* qp =
        q + ((size_t)bh * 4096 + q0 + wave * 32 + s * 16 + l15) * 64 + quad * 8;
    qa0[s] = *(const bf16x8*)(qp);
    qa1[s] = *(const bf16x8*)(qp + 32);
  }

  const int row0 = tid >> 3, off = (tid & 7) * 8;
  const bf16* kp = k + ((size_t)bh * 4096 + row0) * 64 + off;
  const f16*  vp = vt + ((size_t)bh * 64 + row0) * 4096 + off;
  const int lidx = row0 * 72 + off;

  *(uint4*)(lK[0] + lidx)            = *(const uint4*)(kp);
  *(uint4*)(lK[0] + lidx + 32 * 72)  = *(const uint4*)(kp + 32 * 64);
  *(uint4*)(lV[0] + lidx)            = *(const uint4*)(vp);
  *(uint4*)(lV[0] + lidx + 32 * 72)  = *(const uint4*)(vp + 32 * 4096);

  f32x4 accO[2][4] = {};
  f32x4 accD[2] = {};
  const f16x8 vone8 = {(f16)1.0f, (f16)1.0f, (f16)1.0f, (f16)1.0f,
                       (f16)1.0f, (f16)1.0f, (f16)1.0f, (f16)1.0f};
  uint4 pk0, pk1, pv0, pv1;

  for (int it = 0; it < 64; ++it) {
    const int cur = it & 1;
    if (it + 1 < 64) {
      const bf16* kn = kp + (size_t)(it + 1) * 64 * 64;
      const f16*  vn = vp + (it + 1) * 64;
      pk0 = *(const uint4*)(kn);
      pk1 = *(const uint4*)(kn + 32 * 64);
      pv0 = *(const uint4*)(vn);
      pv1 = *(const uint4*)(vn + 32 * 4096);
    }
    __syncthreads();

    f32x4 sf[2][4];
#pragma unroll
    for (int c = 0; c < 4; ++c) {
      const bf16x8 kb0 = *(const bf16x8*)(lK[cur] + (c * 16 + l15) * 72 + quad * 8);
      const bf16x8 kb1 = *(const bf16x8*)(lK[cur] + (c * 16 + l15) * 72 + 32 + quad * 8);
#pragma unroll
      for (int s = 0; s < 2; ++s) {
        f32x4 t = {};
        t = __builtin_amdgcn_mfma_f32_16x16x32_bf16(kb0, qa0[s], t, 0, 0, 0);
        t = __builtin_amdgcn_mfma_f32_16x16x32_bf16(kb1, qa1[s], t, 0, 0, 0);
        sf[s][c] = t;
      }
    }

    f16x8 pa[2][2];
#pragma unroll
    for (int s = 0; s < 2; ++s)
#pragma unroll
      for (int c2 = 0; c2 < 2; ++c2) {
        union { fp16x2 h2[4]; f16x8 h8; } u;
        u.h2[0] = __builtin_amdgcn_cvt_pkrtz(EXP2(sf[s][2 * c2][0]),
                                             EXP2(sf[s][2 * c2][1]));
        u.h2[1] = __builtin_amdgcn_cvt_pkrtz(EXP2(sf[s][2 * c2][2]),
                                             EXP2(sf[s][2 * c2][3]));
        u.h2[2] = __builtin_amdgcn_cvt_pkrtz(EXP2(sf[s][2 * c2 + 1][0]),
                                             EXP2(sf[s][2 * c2 + 1][1]));
        u.h2[3] = __builtin_amdgcn_cvt_pkrtz(EXP2(sf[s][2 * c2 + 1][2]),
                                             EXP2(sf[s][2 * c2 + 1][3]));
        pa[s][c2] = u.h8;
      }

#pragma unroll
    for (int s = 0; s < 2; ++s)
#pragma unroll
      for (int c2 = 0; c2 < 2; ++c2)
        accD[s] = __builtin_amdgcn_mfma_f32_16x16x32_f16(pa[s][c2], vone8,
                                                         accD[s], 0, 0, 0);

#pragma unroll
    for (int c2 = 0; c2 < 2; ++c2) {
#pragma unroll
      for (int n = 0; n < 4; ++n) {
        const f16x8 vb =
            *(const f16x8*)(lV[cur] + (n * 16 + l15) * 72 + c2 * 32 + quad * 8);
#pragma unroll
        for (int s = 0; s < 2; ++s)
          accO[s][n] = __builtin_amdgcn_mfma_f32_16x16x32_f16(pa[s][c2], vb,
                                                              accO[s][n], 0, 0, 0);
      }
    }

    if (it + 1 < 64) {
      *(uint4*)(lK[cur ^ 1] + lidx)           = pk0;
      *(uint4*)(lK[cur ^ 1] + lidx + 32 * 72) = pk1;
      *(uint4*)(lV[cur ^ 1] + lidx)           = pv0;
      *(uint4*)(lV[cur ^ 1] + lidx + 32 * 72) = pv1;
    }
  }

  const int b = bh >> 2, h = bh & 3;
#pragma unroll
  for (int s = 0; s < 2; ++s) {
    float inv[4];
#pragma unroll
    for (int r = 0; r < 4; ++r) inv[r] = 1.0f / accD[s][r];
#pragma unroll
    for (int n = 0; n < 4; ++n)
#pragma unroll
      for (int r = 0; r < 4; ++r) {
        const int t = q0 + wave * 32 + s * 16 + quad * 4 + r;
        o[(size_t)(b * 4096 + t) * 256 + h * 64 + n * 16 + l15] =
            (bf16)(accO[s][n][r] * inv[r]);
      }
  }
}

// ---------------- FFN1: bf16-A GEMM + gelu (R10 structure) ------------------
__global__ __launch_bounds__(256, 2)
void gemm_ffn1_kernel(const bf16* __restrict__ A, const bf16* __restrict__ Wt,
                      const float* __restrict__ bias, bf16* __restrict__ ob) {
  const int tid = threadIdx.x;
  const int wave = tid >> 6, lane = tid & 63;
  const int quad = lane >> 4, l15 = lane & 15;
  const int m0 = blockIdx.y * 128, n0 = blockIdx.x * 128;
  const int mw = (wave >> 1) * 64, nw = (wave & 1) * 64;
  const int K = 256;

  __shared__ bf16 lA[128 * 72];
  __shared__ bf16 lB[128 * 72];

  f32x4 acc[4][4] = {};

  for (int k0 = 0; k0 < K; k0 += 64) {
#pragma unroll
    for (int j = 0; j < 4; ++j) {
      const int c = j * 256 + tid;
      const int row = c >> 3, kc = (c & 7) * 8;
      *(uint4*)(lA + row * 72 + kc) =
          *(const uint4*)(A + (size_t)(m0 + row) * K + k0 + kc);
      *(uint4*)(lB + row * 72 + kc) =
          *(const uint4*)(Wt + (size_t)(n0 + row) * K + k0 + kc);
    }
    __syncthreads();
#pragma unroll
    for (int ks = 0; ks < 2; ++ks) {
      bf16x8 af[4], bfm[4];
#pragma unroll
      for (int i = 0; i < 4; ++i)
        af[i] = *(const bf16x8*)(lA + (mw + i * 16 + l15) * 72 + ks * 32 + quad * 8);
#pragma unroll
      for (int j = 0; j < 4; ++j)
        bfm[j] = *(const bf16x8*)(lB + (nw + j * 16 + l15) * 72 + ks * 32 + quad * 8);
#pragma unroll
      for (int i = 0; i < 4; ++i)
#pragma unroll
        for (int j = 0; j < 4; ++j)
          acc[i][j] = __builtin_amdgcn_mfma_f32_16x16x32_bf16(af[i], bfm[j],
                                                              acc[i][j], 0, 0, 0);
    }
    __syncthreads();
  }

#pragma unroll
  for (int i = 0; i < 4; ++i) {
#pragma unroll
    for (int j = 0; j < 4; ++j) {
      const int n = n0 + nw + j * 16 + l15;
      const float bs = bias[n];
#pragma unroll
      for (int r = 0; r < 4; ++r) {
        const int m = m0 + mw + i * 16 + quad * 4 + r;
        ob[(size_t)m * 768 + n] = (bf16)gelu_exact(acc[i][j][r] + bs);
      }
    }
  }
}

// ---------------- GEMM + bias + residual + LayerNorm, direct-L2 B -----------
// 16-row x 256-col tile, grid M/16 = 1024 (4 blocks/CU). B fragments load
// straight from global (weights are L1/L2-resident); no lB, no B barriers ->
// 1:1 MFMA:buffer_load body with compiler fine-grained vmcnt. lA (4.6 KB)
// double-buffered, one barrier/kt.
template <int KTILES, bool RESID_BF16, bool WRITE_F, bool WRITE_B>
__global__ __launch_bounds__(256, 4)
void gemm_ln_kernel(const bf16* __restrict__ A, const bf16* __restrict__ Wt,
                    const float* __restrict__ bias, const void* __restrict__ Rv,
                    const float* __restrict__ lw, const float* __restrict__ lb,
                    float* __restrict__ outf, bf16* __restrict__ outb) {
  const int tid = threadIdx.x;
  const int wave = tid >> 6, lane = tid & 63;
  const int quad = lane >> 4, l15 = lane & 15;
  const int m0 = blockIdx.x * 16;
  const int nw = wave * 64;
  const int K = KTILES * 64;

  __shared__ bf16 lA[2][16 * 72];
  __shared__ float lnsum[4][16];
  __shared__ float lnsq[4][16];
  __shared__ float lnstat[16][2];

  f32x4 acc[4] = {};  // 4 col subtiles x 1 row subtile

  // B base pointers for this lane's 4 column subtiles
  const bf16* bp[4];
#pragma unroll
  for (int j = 0; j < 4; ++j)
    bp[j] = Wt + (size_t)(nw + j * 16 + l15) * K + quad * 8;

  const int srow = tid >> 3, skc = (tid & 7) * 8;  // threads <128 stage lA
  if (tid < 128)
    *(uint4*)(lA[0] + srow * 72 + skc) =
        *(const uint4*)(A + (size_t)(m0 + srow) * K + skc);

  uint4 pfa;
  for (int kt = 0; kt < KTILES; ++kt) {
    const int cur = kt & 1;
    if (kt + 1 < KTILES && tid < 128)
      pfa = *(const uint4*)(A + (size_t)(m0 + srow) * K + (kt + 1) * 64 + skc);
    __syncthreads();
#pragma unroll
    for (int ks = 0; ks < 2; ++ks) {
      const int kk = kt * 64 + ks * 32;
      bf16x8 bfm[4];
#pragma unroll
      for (int j = 0; j < 4; ++j) bfm[j] = *(const bf16x8*)(bp[j] + kk);
      const bf16x8 af =
          *(const bf16x8*)(lA[cur] + l15 * 72 + ks * 32 + quad * 8);
#pragma unroll
      for (int j = 0; j < 4; ++j)
        acc[j] = __builtin_amdgcn_mfma_f32_16x16x32_bf16(af, bfm[j], acc[j],
                                                         0, 0, 0);
    }
    if (kt + 1 < KTILES && tid < 128)
      *(uint4*)(lA[cur ^ 1] + srow * 72 + skc) = pfa;
  }

  float bv[4], lwv[4], lbv[4];
#pragma unroll
  for (int j = 0; j < 4; ++j) {
    const int col = nw + 16 * j + l15;
    bv[j] = bias[col]; lwv[j] = lw[col]; lbv[j] = lb[col];
  }
  float ps[4] = {}, pq[4] = {};
#pragma unroll
  for (int j = 0; j < 4; ++j) {
#pragma unroll
    for (int r = 0; r < 4; ++r) {
      const int m = m0 + 4 * quad + r;
      const size_t ri = (size_t)m * 256 + nw + 16 * j + l15;
      const float rv = RESID_BF16 ? (float)((const bf16*)Rv)[ri]
                                  : ((const float*)Rv)[ri];
      const float v = acc[j][r] + bv[j] + rv;
      acc[j][r] = v;
      ps[r] += v;
      pq[r] += v * v;
    }
  }
#pragma unroll
  for (int r = 0; r < 4; ++r) {
#pragma unroll
    for (int mm = 1; mm < 16; mm <<= 1) {
      ps[r] += __shfl_xor(ps[r], mm, 64);
      pq[r] += __shfl_xor(pq[r], mm, 64);
    }
    if (l15 == 0) {
      lnsum[wave][4 * quad + r] = ps[r];
      lnsq[wave][4 * quad + r] = pq[r];
    }
  }
  __syncthreads();
  if (tid < 16) {
    const float s = lnsum[0][tid] + lnsum[1][tid] + lnsum[2][tid] + lnsum[3][tid];
    const float sq = lnsq[0][tid] + lnsq[1][tid] + lnsq[2][tid] + lnsq[3][tid];
    const float mean = s * (1.0f / 256.0f);
    const float var = sq * (1.0f / 256.0f) - mean * mean;
    lnstat[tid][0] = mean;
    lnstat[tid][1] = rsqrtf(var + 1e-5f);
  }
  __syncthreads();
#pragma unroll
  for (int r = 0; r < 4; ++r) {
    const int row = 4 * quad + r;
    const float mean = lnstat[row][0], rstd = lnstat[row][1];
#pragma unroll
    for (int j = 0; j < 4; ++j) {
      const float ov = (acc[j][r] - mean) * rstd * lwv[j] + lbv[j];
      const size_t gi = (size_t)(m0 + row) * 256 + nw + 16 * j + l15;
      if constexpr (WRITE_F) outf[gi] = ov;
      if constexpr (WRITE_B) outb[gi] = (bf16)ov;
    }
  }
}

extern "C" void kernel_launch(void* const* d_in, const int* in_sizes, int n_in,
                              void* d_out, int out_size, void* d_ws, size_t ws_size,
                              hipStream_t stream) {
  const float* x      = (const float*)d_in[0];
  const float* qkv_w  = (const float*)d_in[1];
  const float* qkv_b  = (const float*)d_in[2];
  const float* proj_w = (const float*)d_in[3];
  const float* proj_b = (const float*)d_in[4];
  const float* n1_w   = (const float*)d_in[5];
  const float* n1_b   = (const float*)d_in[6];
  const float* ffn_w1 = (const float*)d_in[7];
  const float* ffn_b1 = (const float*)d_in[8];
  const float* ffn_w2 = (const float*)d_in[9];
  const float* ffn_b2 = (const float*)d_in[10];
  const float* n2_w   = (const float*)d_in[11];
  const float* n2_b   = (const float*)d_in[12];
  float* out = (float*)d_out;

  char* ws = (char*)d_ws;
  bf16*  qwt  = (bf16*)(ws + 0);
  bf16*  pwt  = (bf16*)(ws + 393216);
  bf16*  f1wt = (bf16*)(ws + 524288);
  bf16*  f2wt = (bf16*)(ws + 917504);
  bf16*  qb   = (bf16*)(ws + 1310720);
  bf16*  kb   = (bf16*)(ws + 9699328);
  f16*   vtb  = (f16*)(ws + 18087936);
  bf16*  attn = (bf16*)(ws + 26476544);
  bf16*  x1b  = (bf16*)(ws + 34865152);
  bf16*  hbuf = (bf16*)(ws + 1310720);  // aliases qb/kb/vtb (dead by FFN1)

  cvt_w_kernel<<<2560, 256, 0, stream>>>(qkv_w, qwt, proj_w, pwt,
                                         ffn_w1, f1wt, ffn_w2, f2wt);
  gemm_qkv_kernel<<<dim3(6, 128), 256, 0, stream>>>(x, qwt, qkv_b, qb, kb, vtb);
  attn_kernel<<<dim3(32, 16), 256, 0, stream>>>(qb, kb, vtb, attn);
  gemm_ln_kernel<4, false, false, true><<<1024, 256, 0, stream>>>(
      attn, pwt, proj_b, x, n1_w, n1_b, nullptr, x1b);
  gemm_ffn1_kernel<<<dim3(6, 128), 256, 0, stream>>>(x1b, f1wt, ffn_b1, hbuf);
  gemm_ln_kernel<12, true, true, false><<<1024, 256, 0, stream>>>(
      hbuf, f2wt, ffn_b2, x1b, n2_w, n2_b, out, nullptr);
}

// Round 15
// 236.943 us; speedup vs baseline: 1.1672x; 1.1672x over previous
//
#include <hip/hip_runtime.h>
#include <cstdint>
#include <cstddef>

typedef __bf16 bf16;
typedef __bf16 bf16x8 __attribute__((ext_vector_type(8)));
typedef __bf16 bf16x4 __attribute__((ext_vector_type(4)));
typedef _Float16 f16;
typedef _Float16 f16x4 __attribute__((ext_vector_type(4)));
typedef _Float16 f16x8 __attribute__((ext_vector_type(8)));
typedef __fp16 fp16x2 __attribute__((ext_vector_type(2)));
typedef float f32x4 __attribute__((ext_vector_type(4)));

#define DEV static __device__ __forceinline__
#if __has_builtin(__builtin_amdgcn_exp2f)
#define EXP2(x) __builtin_amdgcn_exp2f(x)
#else
#define EXP2(x) exp2f(x)
#endif
#define QSCALE 0.18033688011112042f

DEV float gelu_exact(float v) {
  return 0.5f * v * (1.0f + erff(v * 0.70710678118654752f));
}

// ---------------- coalesced weight transpose: W[K,N] fp32 -> Wt[N,K] bf16 ---
// 64x64 tiles through padded LDS. 160 blocks total.
__global__ void cvt_w_kernel(const float* __restrict__ qkv_w, bf16* __restrict__ qwt,
                             const float* __restrict__ proj_w, bf16* __restrict__ pwt,
                             const float* __restrict__ f1w, bf16* __restrict__ f1wt,
                             const float* __restrict__ f2w, bf16* __restrict__ f2wt) {
  int blk = blockIdx.x;
  const float* w; bf16* o; int K, N;
  if (blk < 48)       { w = qkv_w;  o = qwt;  K = 256; N = 768; }
  else if (blk < 64)  { w = proj_w; o = pwt;  K = 256; N = 256; blk -= 48; }
  else if (blk < 112) { w = f1w;    o = f1wt; K = 256; N = 768; blk -= 64; }
  else                { w = f2w;    o = f2wt; K = 768; N = 256; blk -= 112; }
  const int ntiles = N >> 6;
  const int kt = blk / ntiles, nt = blk - kt * ntiles;
  const int k0 = kt * 64, n0 = nt * 64;
  __shared__ float tile[64][65];
  const int tid = threadIdx.x;
#pragma unroll
  for (int j = 0; j < 4; ++j) {  // load: 1024 float4 chunks, coalesced rows
    const int c = j * 256 + tid;
    const int row = c >> 4, c4 = (c & 15) * 4;
    const float4 v = *(const float4*)(w + (size_t)(k0 + row) * N + n0 + c4);
    tile[row][c4] = v.x; tile[row][c4 + 1] = v.y;
    tile[row][c4 + 2] = v.z; tile[row][c4 + 3] = v.w;
  }
  __syncthreads();
#pragma unroll
  for (int j = 0; j < 4; ++j) {  // store: 1024 bf16x4 chunks, coalesced rows
    const int c = j * 256 + tid;
    const int n = c >> 4, k4 = (c & 15) * 4;
    bf16x4 ov;
#pragma unroll
    for (int i = 0; i < 4; ++i) ov[i] = (bf16)tile[k4 + i][n];
    *(bf16x4*)(o + (size_t)(n0 + n) * K + k0 + k4) = ov;
  }
}

// ---------------- QKV GEMM (fp32 A staged->bf16), R10 structure -------------
__global__ __launch_bounds__(256, 2)
void gemm_qkv_kernel(const float* __restrict__ A, const bf16* __restrict__ Wt,
                     const float* __restrict__ bias, bf16* __restrict__ qb,
                     bf16* __restrict__ kb, f16* __restrict__ vt) {
  const int tid = threadIdx.x;
  const int wave = tid >> 6, lane = tid & 63;
  const int quad = lane >> 4, l15 = lane & 15;
  const int m0 = blockIdx.y * 128, n0 = blockIdx.x * 128;
  const int mw = (wave >> 1) * 64, nw = (wave & 1) * 64;
  const int K = 256;

  __shared__ bf16 lA[128 * 72];
  __shared__ bf16 lB[128 * 72];

  f32x4 acc[4][4] = {};

  for (int k0 = 0; k0 < K; k0 += 64) {
#pragma unroll
    for (int j = 0; j < 4; ++j) {
      const int c = j * 256 + tid;
      const int row = c >> 3, kc = (c & 7) * 8;
      const float* ax = A + (size_t)(m0 + row) * K + k0 + kc;
      const float4 a0 = *(const float4*)(ax);
      const float4 a1 = *(const float4*)(ax + 4);
      bf16x8 ab;
      ab[0] = (bf16)a0.x; ab[1] = (bf16)a0.y; ab[2] = (bf16)a0.z; ab[3] = (bf16)a0.w;
      ab[4] = (bf16)a1.x; ab[5] = (bf16)a1.y; ab[6] = (bf16)a1.z; ab[7] = (bf16)a1.w;
      *(bf16x8*)(lA + row * 72 + kc) = ab;
      *(uint4*)(lB + row * 72 + kc) =
          *(const uint4*)(Wt + (size_t)(n0 + row) * K + k0 + kc);
    }
    __syncthreads();
#pragma unroll
    for (int ks = 0; ks < 2; ++ks) {
      bf16x8 af[4], bfm[4];
#pragma unroll
      for (int i = 0; i < 4; ++i)
        af[i] = *(const bf16x8*)(lA + (mw + i * 16 + l15) * 72 + ks * 32 + quad * 8);
#pragma unroll
      for (int j = 0; j < 4; ++j)
        bfm[j] = *(const bf16x8*)(lB + (nw + j * 16 + l15) * 72 + ks * 32 + quad * 8);
#pragma unroll
      for (int i = 0; i < 4; ++i)
#pragma unroll
        for (int j = 0; j < 4; ++j)
          acc[i][j] = __builtin_amdgcn_mfma_f32_16x16x32_bf16(af[i], bfm[j],
                                                              acc[i][j], 0, 0, 0);
    }
    __syncthreads();
  }

  const bool isV = (n0 >= 512);
#pragma unroll
  for (int i = 0; i < 4; ++i) {
#pragma unroll
    for (int j = 0; j < 4; ++j) {
      const int n = n0 + nw + j * 16 + l15;
      const float bs = bias[n];
      if (isV) {
        const int m = m0 + mw + i * 16 + quad * 4;
        const int b = m >> 12, t = m & 4095;
        const int h = (n >> 6) & 3, d = n & 63;
        const int tp = (t & ~31) | (((t >> 2) & 3) << 3) | (((t >> 4) & 1) << 2);
        f16x4 hv;
#pragma unroll
        for (int r = 0; r < 4; ++r) hv[r] = (f16)(acc[i][j][r] + bs);
        *(f16x4*)(vt + (size_t)((b * 4 + h) * 64 + d) * 4096 + tp) = hv;
      } else {
        const int s = n >> 8, cc = n & 255, h = cc >> 6, d = cc & 63;
#pragma unroll
        for (int r = 0; r < 4; ++r) {
          const int m = m0 + mw + i * 16 + quad * 4 + r;
          const int b = m >> 12, t = m & 4095;
          const float v = acc[i][j][r] + bs;
          const size_t idx = (size_t)((b * 4 + h) * 4096 + t) * 64 + d;
          if (s == 0) qb[idx] = (bf16)(v * QSCALE);
          else        kb[idx] = (bf16)v;
        }
      }
    }
  }
}

// ---------------- flash attention: reg-prefetch dbuf, K=32 PV (R8-R10) ------
__global__ __launch_bounds__(256, 2)
void attn_kernel(const bf16* __restrict__ q, const bf16* __restrict__ k,
                 const f16* __restrict__ vt, bf16* __restrict__ o) {
  const int tid = threadIdx.x;
  const int wave = tid >> 6, lane = tid & 63;
  const int quad = lane >> 4, l15 = lane & 15;
  const int bh = blockIdx.y;
  const int q0 = blockIdx.x * 128;
  __shared__ bf16 lK[2][64 * 72];
  __shared__ f16  lV[2][64 * 72];

  bf16x8 qa0[2], qa1[2];
#pragma unroll
  for (int s = 0; s < 2; ++s) {
    const bf16* qp =
        q + ((size_t)bh * 4096 + q0 + wave * 32 + s * 16 + l15) * 64 + quad * 8;
    qa0[s] = *(const bf16x8*)(qp);
    qa1[s] = *(const bf16x8*)(qp + 32);
  }

  const int row0 = tid >> 3, off = (tid & 7) * 8;
  const bf16* kp = k + ((size_t)bh * 4096 + row0) * 64 + off;
  const f16*  vp = vt + ((size_t)bh * 64 + row0) * 4096 + off;
  const int lidx = row0 * 72 + off;

  *(uint4*)(lK[0] + lidx)            = *(const uint4*)(kp);
  *(uint4*)(lK[0] + lidx + 32 * 72)  = *(const uint4*)(kp + 32 * 64);
  *(uint4*)(lV[0] + lidx)            = *(const uint4*)(vp);
  *(uint4*)(lV[0] + lidx + 32 * 72)  = *(const uint4*)(vp + 32 * 4096);

  f32x4 accO[2][4] = {};
  f32x4 accD[2] = {};
  const f16x8 vone8 = {(f16)1.0f, (f16)1.0f, (f16)1.0f, (f16)1.0f,
                       (f16)1.0f, (f16)1.0f, (f16)1.0f, (f16)1.0f};
  uint4 pk0, pk1, pv0, pv1;

  for (int it = 0; it < 64; ++it) {
    const int cur = it & 1;
    if (it + 1 < 64) {
      const bf16* kn = kp + (size_t)(it + 1) * 64 * 64;
      const f16*  vn = vp + (it + 1) * 64;
      pk0 = *(const uint4*)(kn);
      pk1 = *(const uint4*)(kn + 32 * 64);
      pv0 = *(const uint4*)(vn);
      pv1 = *(const uint4*)(vn + 32 * 4096);
    }
    __syncthreads();

    f32x4 sf[2][4];
#pragma unroll
    for (int c = 0; c < 4; ++c) {
      const bf16x8 kb0 = *(const bf16x8*)(lK[cur] + (c * 16 + l15) * 72 + quad * 8);
      const bf16x8 kb1 = *(const bf16x8*)(lK[cur] + (c * 16 + l15) * 72 + 32 + quad * 8);
#pragma unroll
      for (int s = 0; s < 2; ++s) {
        f32x4 t = {};
        t = __builtin_amdgcn_mfma_f32_16x16x32_bf16(kb0, qa0[s], t, 0, 0, 0);
        t = __builtin_amdgcn_mfma_f32_16x16x32_bf16(kb1, qa1[s], t, 0, 0, 0);
        sf[s][c] = t;
      }
    }

    f16x8 pa[2][2];
#pragma unroll
    for (int s = 0; s < 2; ++s)
#pragma unroll
      for (int c2 = 0; c2 < 2; ++c2) {
        union { fp16x2 h2[4]; f16x8 h8; } u;
        u.h2[0] = __builtin_amdgcn_cvt_pkrtz(EXP2(sf[s][2 * c2][0]),
                                             EXP2(sf[s][2 * c2][1]));
        u.h2[1] = __builtin_amdgcn_cvt_pkrtz(EXP2(sf[s][2 * c2][2]),
                                             EXP2(sf[s][2 * c2][3]));
        u.h2[2] = __builtin_amdgcn_cvt_pkrtz(EXP2(sf[s][2 * c2 + 1][0]),
                                             EXP2(sf[s][2 * c2 + 1][1]));
        u.h2[3] = __builtin_amdgcn_cvt_pkrtz(EXP2(sf[s][2 * c2 + 1][2]),
                                             EXP2(sf[s][2 * c2 + 1][3]));
        pa[s][c2] = u.h8;
      }

#pragma unroll
    for (int s = 0; s < 2; ++s)
#pragma unroll
      for (int c2 = 0; c2 < 2; ++c2)
        accD[s] = __builtin_amdgcn_mfma_f32_16x16x32_f16(pa[s][c2], vone8,
                                                         accD[s], 0, 0, 0);

#pragma unroll
    for (int c2 = 0; c2 < 2; ++c2) {
#pragma unroll
      for (int n = 0; n < 4; ++n) {
        const f16x8 vb =
            *(const f16x8*)(lV[cur] + (n * 16 + l15) * 72 + c2 * 32 + quad * 8);
#pragma unroll
        for (int s = 0; s < 2; ++s)
          accO[s][n] = __builtin_amdgcn_mfma_f32_16x16x32_f16(pa[s][c2], vb,
                                                              accO[s][n], 0, 0, 0);
      }
    }

    if (it + 1 < 64) {
      *(uint4*)(lK[cur ^ 1] + lidx)           = pk0;
      *(uint4*)(lK[cur ^ 1] + lidx + 32 * 72) = pk1;
      *(uint4*)(lV[cur ^ 1] + lidx)           = pv0;
      *(uint4*)(lV[cur ^ 1] + lidx + 32 * 72) = pv1;
    }
  }

  const int b = bh >> 2, h = bh & 3;
#pragma unroll
  for (int s = 0; s < 2; ++s) {
    float inv[4];
#pragma unroll
    for (int r = 0; r < 4; ++r) inv[r] = 1.0f / accD[s][r];
#pragma unroll
    for (int n = 0; n < 4; ++n)
#pragma unroll
      for (int r = 0; r < 4; ++r) {
        const int t = q0 + wave * 32 + s * 16 + quad * 4 + r;
        o[(size_t)(b * 4096 + t) * 256 + h * 64 + n * 16 + l15] =
            (bf16)(accO[s][n][r] * inv[r]);
      }
  }
}

// ---------------- FFN1: bf16-A GEMM + gelu (R10 structure) ------------------
__global__ __launch_bounds__(256, 2)
void gemm_ffn1_kernel(const bf16* __restrict__ A, const bf16* __restrict__ Wt,
                      const float* __restrict__ bias, bf16* __restrict__ ob) {
  const int tid = threadIdx.x;
  const int wave = tid >> 6, lane = tid & 63;
  const int quad = lane >> 4, l15 = lane & 15;
  const int m0 = blockIdx.y * 128, n0 = blockIdx.x * 128;
  const int mw = (wave >> 1) * 64, nw = (wave & 1) * 64;
  const int K = 256;

  __shared__ bf16 lA[128 * 72];
  __shared__ bf16 lB[128 * 72];

  f32x4 acc[4][4] = {};

  for (int k0 = 0; k0 < K; k0 += 64) {
#pragma unroll
    for (int j = 0; j < 4; ++j) {
      const int c = j * 256 + tid;
      const int row = c >> 3, kc = (c & 7) * 8;
      *(uint4*)(lA + row * 72 + kc) =
          *(const uint4*)(A + (size_t)(m0 + row) * K + k0 + kc);
      *(uint4*)(lB + row * 72 + kc) =
          *(const uint4*)(Wt + (size_t)(n0 + row) * K + k0 + kc);
    }
    __syncthreads();
#pragma unroll
    for (int ks = 0; ks < 2; ++ks) {
      bf16x8 af[4], bfm[4];
#pragma unroll
      for (int i = 0; i < 4; ++i)
        af[i] = *(const bf16x8*)(lA + (mw + i * 16 + l15) * 72 + ks * 32 + quad * 8);
#pragma unroll
      for (int j = 0; j < 4; ++j)
        bfm[j] = *(const bf16x8*)(lB + (nw + j * 16 + l15) * 72 + ks * 32 + quad * 8);
#pragma unroll
      for (int i = 0; i < 4; ++i)
#pragma unroll
        for (int j = 0; j < 4; ++j)
          acc[i][j] = __builtin_amdgcn_mfma_f32_16x16x32_bf16(af[i], bfm[j],
                                                              acc[i][j], 0, 0, 0);
    }
    __syncthreads();
  }

#pragma unroll
  for (int i = 0; i < 4; ++i) {
#pragma unroll
    for (int j = 0; j < 4; ++j) {
      const int n = n0 + nw + j * 16 + l15;
      const float bs = bias[n];
#pragma unroll
      for (int r = 0; r < 4; ++r) {
        const int m = m0 + mw + i * 16 + quad * 4 + r;
        ob[(size_t)m * 768 + n] = (bf16)gelu_exact(acc[i][j][r] + bs);
      }
    }
  }
}

// ---------------- GEMM + bias + residual + LayerNorm fused (R10) ------------
// 32-row x 256-col tile (full LN rows), grid M/32 = 512.
template <int KTILES, bool RESID_BF16, bool WRITE_F, bool WRITE_B>
__global__ __launch_bounds__(256, 3)
void gemm_ln_kernel(const bf16* __restrict__ A, const bf16* __restrict__ Wt,
                    const float* __restrict__ bias, const void* __restrict__ Rv,
                    const float* __restrict__ lw, const float* __restrict__ lb,
                    float* __restrict__ outf, bf16* __restrict__ outb) {
  const int tid = threadIdx.x;
  const int wave = tid >> 6, lane = tid & 63;
  const int quad = lane >> 4, l15 = lane & 15;
  const int m0 = blockIdx.x * 32;
  const int nw = wave * 64;
  const int K = KTILES * 64;
  __shared__ bf16 lA[32 * 72];
  __shared__ bf16 lB[256 * 72];
  __shared__ float lnsum[4][32];
  __shared__ float lnsq[4][32];
  __shared__ float lnstat[32][2];
  f32x4 acc[2][4] = {};

  for (int kt = 0; kt < KTILES; ++kt) {
    const int k0 = kt * 64;
    {
      const int row = tid >> 3, kc = (tid & 7) * 8;
      *(uint4*)(lA + row * 72 + kc) =
          *(const uint4*)(A + (size_t)(m0 + row) * K + k0 + kc);
    }
#pragma unroll
    for (int j = 0; j < 8; ++j) {
      const int c = j * 256 + tid;
      const int row = c >> 3, kc = (c & 7) * 8;
      *(uint4*)(lB + row * 72 + kc) =
          *(const uint4*)(Wt + (size_t)row * K + k0 + kc);
    }
    __syncthreads();
#pragma unroll
    for (int ks = 0; ks < 2; ++ks) {
      bf16x8 af[2], bfm[4];
#pragma unroll
      for (int i = 0; i < 2; ++i)
        af[i] = *(const bf16x8*)(lA + (i * 16 + l15) * 72 + ks * 32 + quad * 8);
#pragma unroll
      for (int j = 0; j < 4; ++j)
        bfm[j] = *(const bf16x8*)(lB + (nw + j * 16 + l15) * 72 + ks * 32 + quad * 8);
#pragma unroll
      for (int i = 0; i < 2; ++i)
#pragma unroll
        for (int j = 0; j < 4; ++j)
          acc[i][j] = __builtin_amdgcn_mfma_f32_16x16x32_bf16(af[i], bfm[j],
                                                              acc[i][j], 0, 0, 0);
    }
    __syncthreads();
  }

  float bv[4], lwv[4], lbv[4];
#pragma unroll
  for (int j = 0; j < 4; ++j) {
    const int col = nw + 16 * j + l15;
    bv[j] = bias[col]; lwv[j] = lw[col]; lbv[j] = lb[col];
  }
#pragma unroll
  for (int i = 0; i < 2; ++i) {
    float ps[4] = {}, pq[4] = {};
#pragma unroll
    for (int j = 0; j < 4; ++j) {
#pragma unroll
      for (int r = 0; r < 4; ++r) {
        const int m = m0 + 16 * i + 4 * quad + r;
        const size_t ri = (size_t)m * 256 + nw + 16 * j + l15;
        const float rv = RESID_BF16 ? (float)((const bf16*)Rv)[ri]
                                    : ((const float*)Rv)[ri];
        const float v = acc[i][j][r] + bv[j] + rv;
        acc[i][j][r] = v;
        ps[r] += v;
        pq[r] += v * v;
      }
    }
#pragma unroll
    for (int r = 0; r < 4; ++r) {
#pragma unroll
      for (int mm = 1; mm < 16; mm <<= 1) {
        ps[r] += __shfl_xor(ps[r], mm, 64);
        pq[r] += __shfl_xor(pq[r], mm, 64);
      }
      if (l15 == 0) {
        lnsum[wave][16 * i + 4 * quad + r] = ps[r];
        lnsq[wave][16 * i + 4 * quad + r] = pq[r];
      }
    }
  }
  __syncthreads();
  if (tid < 32) {
    const float s = lnsum[0][tid] + lnsum[1][tid] + lnsum[2][tid] + lnsum[3][tid];
    const float sq = lnsq[0][tid] + lnsq[1][tid] + lnsq[2][tid] + lnsq[3][tid];
    const float mean = s * (1.0f / 256.0f);
    const float var = sq * (1.0f / 256.0f) - mean * mean;
    lnstat[tid][0] = mean;
    lnstat[tid][1] = rsqrtf(var + 1e-5f);
  }
  __syncthreads();
#pragma unroll
  for (int i = 0; i < 2; ++i) {
#pragma unroll
    for (int r = 0; r < 4; ++r) {
      const int row = 16 * i + 4 * quad + r;
      const float mean = lnstat[row][0], rstd = lnstat[row][1];
#pragma unroll
      for (int j = 0; j < 4; ++j) {
        const float ov = (acc[i][j][r] - mean) * rstd * lwv[j] + lbv[j];
        const size_t gi = (size_t)(m0 + row) * 256 + nw + 16 * j + l15;
        if constexpr (WRITE_F) outf[gi] = ov;
        if constexpr (WRITE_B) outb[gi] = (bf16)ov;
      }
    }
  }
}

extern "C" void kernel_launch(void* const* d_in, const int* in_sizes, int n_in,
                              void* d_out, int out_size, void* d_ws, size_t ws_size,
                              hipStream_t stream) {
  const float* x      = (const float*)d_in[0];
  const float* qkv_w  = (const float*)d_in[1];
  const float* qkv_b  = (const float*)d_in[2];
  const float* proj_w = (const float*)d_in[3];
  const float* proj_b = (const float*)d_in[4];
  const float* n1_w   = (const float*)d_in[5];
  const float* n1_b   = (const float*)d_in[6];
  const float* ffn_w1 = (const float*)d_in[7];
  const float* ffn_b1 = (const float*)d_in[8];
  const float* ffn_w2 = (const float*)d_in[9];
  const float* ffn_b2 = (const float*)d_in[10];
  const float* n2_w   = (const float*)d_in[11];
  const float* n2_b   = (const float*)d_in[12];
  float* out = (float*)d_out;

  char* ws = (char*)d_ws;
  bf16*  qwt  = (bf16*)(ws + 0);
  bf16*  pwt  = (bf16*)(ws + 393216);
  bf16*  f1wt = (bf16*)(ws + 524288);
  bf16*  f2wt = (bf16*)(ws + 917504);
  bf16*  qb   = (bf16*)(ws + 1310720);
  bf16*  kb   = (bf16*)(ws + 9699328);
  f16*   vtb  = (f16*)(ws + 18087936);
  bf16*  attn = (bf16*)(ws + 26476544);
  bf16*  x1b  = (bf16*)(ws + 34865152);
  bf16*  hbuf = (bf16*)(ws + 1310720);  // aliases qb/kb/vtb (dead by FFN1)

  cvt_w_kernel<<<160, 256, 0, stream>>>(qkv_w, qwt, proj_w, pwt,
                                        ffn_w1, f1wt, ffn_w2, f2wt);
  gemm_qkv_kernel<<<dim3(6, 128), 256, 0, stream>>>(x, qwt, qkv_b, qb, kb, vtb);
  attn_kernel<<<dim3(32, 16), 256, 0, stream>>>(qb, kb, vtb, attn);
  gemm_ln_kernel<4, false, false, true><<<512, 256, 0, stream>>>(
      attn, pwt, proj_b, x, n1_w, n1_b, nullptr, x1b);
  gemm_ffn1_kernel<<<dim3(6, 128), 256, 0, stream>>>(x1b, f1wt, ffn_b1, hbuf);
  gemm_ln_kernel<12, true, true, false><<<512, 256, 0, stream>>>(
      hbuf, f2wt, ffn_b2, x1b, n2_w, n2_b, out, nullptr);
}